// Round 8
// baseline (928.661 us; speedup 1.0000x reference)
//
#include <hip/hip_runtime.h>
#include <hip/hip_bf16.h>
#include <cstddef>

typedef unsigned short u16;
typedef u16 u16x8 __attribute__((ext_vector_type(8)));
typedef __bf16 bf16x8 __attribute__((ext_vector_type(8)));
typedef float f32x4 __attribute__((ext_vector_type(4)));
typedef int i32x4 __attribute__((ext_vector_type(4)));

__device__ __forceinline__ u16 f2b(float f) {
  unsigned int u = __float_as_uint(f);
  unsigned int r = 0x7FFFu + ((u >> 16) & 1u);
  return (u16)((u + r) >> 16);
}
__device__ __forceinline__ float b2f(u16 u) {
  return __uint_as_float(((unsigned int)u) << 16);
}

// ---------------- bf16 MFMA GEMM: C[M,256] = A[M,K](fp32) @ Wt[256,K](bf16)^T --------
// BM=64 x BN=256 tile (full output width per block): each A-tile staged ONCE.
// 256 threads = 4 waves, wave w owns rows 0..63 x cols [64w, 64w+64).
// LDS 40 KB. XOR-swizzled LDS (c ^= row&7) keeps ds_read_b128 conflict-free.
template <bool OUT_BF16>
__global__ __launch_bounds__(256) void gemm_bf16(
    const float* __restrict__ A, const u16* __restrict__ Bt, void* __restrict__ Cv,
    int M, int K) {
  __shared__ u16 As[64 * 64];
  __shared__ u16 Bs[256 * 64];
  const int tid = threadIdx.x;
  const int wid = tid >> 6;
  const int lane = tid & 63;
  const int brow = blockIdx.x * 64;
  const int waveN = wid * 64;
  const int q = lane >> 4;
  const int rl = lane & 15;

  f32x4 acc[4][4] = {};

  const int arow = tid >> 2;         // 0..63
  const int kq = (tid & 3) * 16;     // 0,16,32,48
  const int garow = brow + arow;
  const bool aok = garow < M;
  const int aswz = arow & 7;
  const int brb = tid;               // 0..255
  const int bswz = brb & 7;

  for (int k0 = 0; k0 < K; k0 += 64) {
    {  // stage A (fp32 -> bf16)
      const float* src = A + (size_t)garow * K + k0 + kq;
      u16* dstrow = As + arow * 64;
#pragma unroll
      for (int j = 0; j < 2; ++j) {
        float4 v0 = make_float4(0.f, 0.f, 0.f, 0.f), v1 = v0;
        if (aok) {
          v0 = *(const float4*)(src + j * 8);
          v1 = *(const float4*)(src + j * 8 + 4);
        }
        u16x8 v = {f2b(v0.x), f2b(v0.y), f2b(v0.z), f2b(v0.w),
                   f2b(v1.x), f2b(v1.y), f2b(v1.z), f2b(v1.w)};
        const int c = (kq >> 3) + j;
        *(u16x8*)(dstrow + 8 * (c ^ aswz)) = v;
      }
    }
    {  // stage Bt (already bf16): full 128 B row per thread
      const u16* src = Bt + (size_t)brb * K + k0;
      u16* dstrow = Bs + brb * 64;
#pragma unroll
      for (int j = 0; j < 8; ++j) {
        u16x8 v = *(const u16x8*)(src + j * 8);
        *(u16x8*)(dstrow + 8 * (j ^ bswz)) = v;
      }
    }
    __syncthreads();
#pragma unroll
    for (int ks = 0; ks < 2; ++ks) {
      bf16x8 af[4], bfr[4];
      const int cbase = ks * 4 + q;
#pragma unroll
      for (int i = 0; i < 4; ++i) {
        const int r = 16 * i + rl;
        af[i] = __builtin_bit_cast(bf16x8,
                 *(const u16x8*)(As + r * 64 + 8 * (cbase ^ (rl & 7))));
      }
#pragma unroll
      for (int j = 0; j < 4; ++j) {
        const int r = waveN + 16 * j + rl;
        bfr[j] = __builtin_bit_cast(bf16x8,
                  *(const u16x8*)(Bs + r * 64 + 8 * (cbase ^ (rl & 7))));
      }
#pragma unroll
      for (int i = 0; i < 4; ++i)
#pragma unroll
        for (int j = 0; j < 4; ++j)
          acc[i][j] = __builtin_amdgcn_mfma_f32_16x16x32_bf16(af[i], bfr[j], acc[i][j], 0, 0, 0);
    }
    __syncthreads();
  }

  // epilogue: C/D layout col=lane&15, row=quad*4+reg
#pragma unroll
  for (int i = 0; i < 4; ++i) {
#pragma unroll
    for (int reg = 0; reg < 4; ++reg) {
      const int gr = brow + 16 * i + q * 4 + reg;
      if (gr >= M) continue;
#pragma unroll
      for (int j = 0; j < 4; ++j) {
        const int col = waveN + 16 * j + rl;
        const float v = acc[i][j][reg];
        if (OUT_BF16) ((u16*)Cv)[(size_t)gr * 256 + col] = f2b(v);
        else          ((float*)Cv)[(size_t)gr * 256 + col] = v;
      }
    }
  }
}

// ---------------- W[K][256] fp32 -> Wt[256][K] bf16 ----------------
__global__ __launch_bounds__(256) void conv_wt(const float* __restrict__ W,
                                               u16* __restrict__ Wt, int K) {
  const int idx = blockIdx.x * 256 + threadIdx.x;  // over K*256
  const int k = idx >> 8;
  const int n = idx & 255;
  if (k < K) Wt[(size_t)n * K + k] = f2b(W[idx]);
}

// ---------------- CSR build: two-level counting bucket sort, LDS atomics only -------
#define EB   256   // edge chunks (blocks) for pass A
#define RPB  128   // rows per coarse bucket
#define NBUK 391   // ceil(50048/128); covers rows 0..50047 for N=50000

// per-block edge range, padded to a multiple of 4 for aligned int4 loads
__device__ __forceinline__ void edge_range(int E, int blk, int& s, int& e) {
  const int per = (((E + EB - 1) / EB) + 3) & ~3;
  s = blk * per;
  e = min(E, s + per);
}

__global__ __launch_bounds__(256) void pa_hist(const int* __restrict__ row,
                                               int* __restrict__ ghist, int E) {
  __shared__ int h[NBUK];
  for (int i = threadIdx.x; i < NBUK; i += 256) h[i] = 0;
  __syncthreads();
  int s, e;
  edge_range(E, blockIdx.x, s, e);
  for (int i = s + threadIdx.x * 4; i < e; i += 1024) {
    if (i + 3 < e) {
      const i32x4 rr = __builtin_nontemporal_load((const i32x4*)(row + i));
#pragma unroll
      for (int j = 0; j < 4; ++j) atomicAdd(&h[rr[j] >> 7], 1);
    } else {
      for (int i2 = i; i2 < e; ++i2) atomicAdd(&h[row[i2] >> 7], 1);
    }
  }
  __syncthreads();
  for (int i = threadIdx.x; i < NBUK; i += 256) ghist[i * EB + blockIdx.x] = h[i];
}

__global__ __launch_bounds__(256) void pa_scatter(
    const int* __restrict__ row, const int* __restrict__ col, const float* __restrict__ ew,
    const int* __restrict__ gscan, int2* __restrict__ tmp, int E) {
  __shared__ int cur[NBUK];
  for (int i = threadIdx.x; i < NBUK; i += 256) cur[i] = gscan[i * EB + blockIdx.x];
  __syncthreads();
  int s, e;
  edge_range(E, blockIdx.x, s, e);
  for (int i0 = s + threadIdx.x * 4; i0 < e; i0 += 1024) {
    if (i0 + 3 < e) {
      const i32x4 r4 = __builtin_nontemporal_load((const i32x4*)(row + i0));
      const i32x4 c4 = __builtin_nontemporal_load((const i32x4*)(col + i0));
      const f32x4 w4 = __builtin_nontemporal_load((const f32x4*)(ew + i0));
#pragma unroll
      for (int j = 0; j < 4; ++j) {
        const int pos = atomicAdd(&cur[r4[j] >> 7], 1);
        tmp[pos] = make_int2(((r4[j] & 127) << 16) | c4[j], __float_as_int(w4[j]));
      }
    } else {
      for (int i2 = i0; i2 < e; ++i2) {
        const int r = row[i2];
        const int pos = atomicAdd(&cur[r >> 7], 1);
        tmp[pos] = make_int2(((r & 127) << 16) | col[i2], __float_as_int(ew[i2]));
      }
    }
  }
}

__global__ __launch_bounds__(256) void pb_sort(
    const int2* __restrict__ tmp, const int* __restrict__ gscan,
    int2* __restrict__ sedge, int* __restrict__ offs, int E, int N) {
  __shared__ int h[RPB];
  __shared__ int sc[RPB];
  __shared__ int cur[RPB];
  const int b = blockIdx.x;
  const int t = threadIdx.x;
  const int base = gscan[b * EB];
  const int end = (b == NBUK - 1) ? E : gscan[(b + 1) * EB];
  if (t < RPB) h[t] = 0;
  __syncthreads();
  for (int i = base + t; i < end; i += 256) atomicAdd(&h[(tmp[i].x >> 16) & 127], 1);
  __syncthreads();
  if (t < RPB) sc[t] = h[t];
  __syncthreads();
  for (int off = 1; off < RPB; off <<= 1) {
    int x = (t >= off && t < RPB) ? sc[t - off] : 0;
    __syncthreads();
    if (t < RPB) sc[t] += x;
    __syncthreads();
  }
  if (t < RPB) {
    const int ex = base + sc[t] - h[t];
    cur[t] = ex;
    const int rg = b * RPB + t;
    if (rg <= N) offs[rg] = ex;   // rg==N lands exactly at E
  }
  __syncthreads();
  for (int i = base + t; i < end; i += 256) {
    const int2 v = tmp[i];
    const int pos = atomicAdd(&cur[(v.x >> 16) & 127], 1);
    sedge[pos] = make_int2(v.x & 0xFFFF, v.y);
  }
}

// ---------------- scan helpers ----------------
__global__ __launch_bounds__(256) void scan1(const int* __restrict__ deg,
                                             int* __restrict__ offs,
                                             int* __restrict__ partials, int n) {
  __shared__ int sh[256];
  const int t = threadIdx.x;
  const int base = blockIdx.x * 1024 + t * 4;
  int v[4];
#pragma unroll
  for (int j = 0; j < 4; j++) v[j] = (base + j < n) ? deg[base + j] : 0;
  const int tsum = v[0] + v[1] + v[2] + v[3];
  sh[t] = tsum;
  __syncthreads();
  for (int off = 1; off < 256; off <<= 1) {
    int x = (t >= off) ? sh[t - off] : 0;
    __syncthreads();
    sh[t] += x;
    __syncthreads();
  }
  if (t == 255) partials[blockIdx.x] = sh[255];
  int run = sh[t] - tsum;
#pragma unroll
  for (int j = 0; j < 4; j++) {
    if (base + j < n) offs[base + j] = run;
    run += v[j];
  }
}

__global__ void scan2(int* __restrict__ partials, int nb) {
  if (threadIdx.x == 0 && blockIdx.x == 0) {
    int run = 0;
    for (int i = 0; i < nb; i++) {
      int t = partials[i];
      partials[i] = run;
      run += t;
    }
  }
}

__global__ __launch_bounds__(256) void scan_add(int* __restrict__ a,
                                                const int* __restrict__ partials, int n) {
  const int t = threadIdx.x;
  const int base = blockIdx.x * 1024 + t * 4;
  const int add = partials[blockIdx.x];
#pragma unroll
  for (int j = 0; j < 4; j++)
    if (base + j < n) a[base + j] += add;
}

// ------- slice aggregate: dim-sliced gather so each XCD's gathers are L2-resident ---
// grid (8, ceil(N/4)): blockIdx.x = dim-slice (32 dims, 64 B of each hpb row).
// Consecutive blockIdx round-robin the 8 XCDs -> slice s pinned to XCD s; the
// slice's gather footprint is 50000 x 64 B = 3.2 MB < 4 MB L2. This converts the
// fabric-bound random gather (819 MB, ~45% L2 miss, 3.3 TB/s ceiling measured
// r4/r5) into local-L2 hits. sedge/res are NT so they don't evict the slice.
// Wave = one row: 16 edges/iter (4 lanes x 16 B per edge), x2 unrolled.
// Residual added here; result written to hag (= the out buffer; for type1
// hag==res, safe: per-thread read-then-write of the same address).
__global__ __launch_bounds__(256) void agg_slice(
    const u16* __restrict__ hpb, const int* __restrict__ offs,
    const int2* __restrict__ sedge, const float* __restrict__ res,
    float* __restrict__ hag, int nrows) {
  const int wave = threadIdx.x >> 6;
  const int lane = threadIdx.x & 63;
  const int r = blockIdx.y * 4 + wave;
  if (r >= nrows) return;
  const int s = blockIdx.x;            // slice 0..7
  const int g = lane >> 2;             // edge group 0..15
  const int dbase = s * 32 + (lane & 3) * 8;
  const long long* sedge8 = (const long long*)sedge;

  float acc[8] = {0.f, 0.f, 0.f, 0.f, 0.f, 0.f, 0.f, 0.f};
  const int kbeg = offs[r], kend = offs[r + 1];
  for (int k = kbeg; k < kend; k += 32) {
    const int e0 = k + g, e1 = k + 16 + g;
    const bool k0 = e0 < kend, k1 = e1 < kend;
    long long ed0 = 0, ed1 = 0;
    if (k0) ed0 = __builtin_nontemporal_load(sedge8 + e0);
    if (k1) ed1 = __builtin_nontemporal_load(sedge8 + e1);
    u16x8 h0 = {}, h1 = {};
    if (k0) h0 = *(const u16x8*)(hpb + (size_t)(int)ed0 * 256 + dbase);
    if (k1) h1 = *(const u16x8*)(hpb + (size_t)(int)ed1 * 256 + dbase);
    if (k0) {
      const float w = __int_as_float((int)(ed0 >> 32));
#pragma unroll
      for (int d = 0; d < 8; ++d) acc[d] += w * b2f(h0[d]);
    }
    if (k1) {
      const float w = __int_as_float((int)(ed1 >> 32));
#pragma unroll
      for (int d = 0; d < 8; ++d) acc[d] += w * b2f(h1[d]);
    }
  }

  // reduce the 16 edge-groups (lane bits 2..5); every lane ends with full sums
#pragma unroll
  for (int m = 4; m <= 32; m <<= 1)
#pragma unroll
    for (int d = 0; d < 8; ++d) acc[d] += __shfl_xor(acc[d], m);

  // lanes 0..7 write the 32-dim slice (+residual), 16 B each, 128 B contiguous
  if (lane < 8) {
    float a4[4];
    if (lane < 4) { a4[0] = acc[0]; a4[1] = acc[1]; a4[2] = acc[2]; a4[3] = acc[3]; }
    else          { a4[0] = acc[4]; a4[1] = acc[5]; a4[2] = acc[6]; a4[3] = acc[7]; }
    const size_t off = (size_t)r * 256 + s * 32 + (lane & 3) * 8 + (lane >> 2) * 4;
    const f32x4 rv = __builtin_nontemporal_load((const f32x4*)(res + off));
    f32x4 o;
#pragma unroll
    for (int d = 0; d < 4; ++d) o[d] = a4[d] + rv[d];
    __builtin_nontemporal_store(o, (f32x4*)(hag + off));
  }
}

// ------- in-place row LayerNorm over [N][256] fp32 -------
__global__ __launch_bounds__(256) void ln_rows(
    const float* __restrict__ hag, const float* __restrict__ g, const float* __restrict__ b,
    float* __restrict__ out, int nrows) {
  const int wave = threadIdx.x >> 6;
  const int lane = threadIdx.x & 63;
  const int r = blockIdx.x * 4 + wave;
  if (r >= nrows) return;
  const int f4 = lane * 4;
  f32x4 v = __builtin_nontemporal_load((const f32x4*)(hag + (size_t)r * 256 + f4));
  float s = v[0] + v[1] + v[2] + v[3];
#pragma unroll
  for (int m = 32; m >= 1; m >>= 1) s += __shfl_xor(s, m);
  const float mu = s * (1.f / 256.f);
#pragma unroll
  for (int d = 0; d < 4; ++d) v[d] -= mu;
  float ss = v[0] * v[0] + v[1] * v[1] + v[2] * v[2] + v[3] * v[3];
#pragma unroll
  for (int m = 32; m >= 1; m >>= 1) ss += __shfl_xor(ss, m);
  const float rs = rsqrtf(ss * (1.f / 256.f) + 1e-5f);
  const float4 gg = *(const float4*)(g + f4);
  const float4 bb = *(const float4*)(b + f4);
  f32x4 o;
  o[0] = v[0] * rs * gg.x + bb.x;
  o[1] = v[1] * rs * gg.y + bb.y;
  o[2] = v[2] * rs * gg.z + bb.z;
  o[3] = v[3] * rs * gg.w + bb.w;
  __builtin_nontemporal_store(o, (f32x4*)(out + (size_t)r * 256 + f4));
}

extern "C" void kernel_launch(void* const* d_in, const int* in_sizes, int n_in,
                              void* d_out, int out_size, void* d_ws, size_t ws_size,
                              hipStream_t stream) {
  const float* x0    = (const float*)d_in[0];
  const float* x1    = (const float*)d_in[1];
  const float* W0    = (const float*)d_in[2];
  const float* W1    = (const float*)d_in[3];
  const float* Wres1 = (const float*)d_in[4];
  const float* g0    = (const float*)d_in[5];
  const float* b0    = (const float*)d_in[6];
  const float* g1    = (const float*)d_in[7];
  const float* b1    = (const float*)d_in[8];
  const float* ew0   = (const float*)d_in[9];
  const float* ew1   = (const float*)d_in[10];
  const int*   row0  = (const int*)d_in[11];
  const int*   col0  = (const int*)d_in[12];
  const int*   row1  = (const int*)d_in[13];
  const int*   col1  = (const int*)d_in[14];
  float* out = (float*)d_out;

  const int N = 50000, D0 = 256, D1 = 512, DO = 256, E = 1600000;

  // ws layout (bytes, 16B-aligned)
  char* w = (char*)d_ws;
  u16*   hpb   = (u16*)  (w);                  // 25,600,000
  u16*   wtb   = (u16*)  (w + 25600000);       //    262,144 (max 512x256 bf16)
  int2*  sedge = (int2*) (w + 25862144);       // 12,800,000 (packed col+ew, CSR order)
  int*   offs  = (int*)  (w + 38662144);       //    200,004 (N+1)
  int*   ghist = (int*)  (w + 38862160);       //    400,384 (NBUK*EB ints)
  int*   parts = (int*)  (w + 39262560);       //        392
  // tmp aliases hpb: hpb is dead during both CSR builds.
  int2*  tmp   = (int2*) (w);                  // 12,800,000 (aliases hpb)

  float* out0 = out;
  float* out1 = out + (size_t)N * DO;

  const dim3 blk(256);
  const dim3 gemm_grid((N + 63) / 64);         // 782 row-tiles, full DO width each
  const dim3 slice_grid(8, (N + 3) / 4);       // x = dim-slice (XCD-pinned), y = row-chunk
  const dim3 ln_grid((N + 3) / 4);
  const int NGH = NBUK * EB;                   // 100,096
  const int NBS = (NGH + 1023) / 1024;         // 98

  auto build_csr = [&](const int* row, const int* col, const float* ew) {
    pa_hist<<<dim3(EB), blk, 0, stream>>>(row, ghist, E);
    scan1<<<dim3(NBS), blk, 0, stream>>>(ghist, ghist, parts, NGH);
    scan2<<<dim3(1), dim3(64), 0, stream>>>(parts, NBS);
    scan_add<<<dim3(NBS), blk, 0, stream>>>(ghist, parts, NGH);
    pa_scatter<<<dim3(EB), blk, 0, stream>>>(row, col, ew, ghist, tmp, E);
    pb_sort<<<dim3(NBUK), blk, 0, stream>>>(tmp, ghist, sedge, offs, E, N);
  };

  // ---- type 0: identity residual ----
  build_csr(row0, col0, ew0);
  conv_wt<<<dim3(D0), blk, 0, stream>>>(W0, wtb, D0);
  gemm_bf16<true><<<gemm_grid, blk, 0, stream>>>(x0, wtb, hpb, N, D0);
  agg_slice<<<slice_grid, blk, 0, stream>>>(hpb, offs, sedge, x0, out0, N);
  ln_rows<<<ln_grid, blk, 0, stream>>>(out0, g0, b0, out0, N);

  // ---- type 1: projected residual ----
  conv_wt<<<dim3(D1), blk, 0, stream>>>(Wres1, wtb, D1);
  gemm_bf16<false><<<gemm_grid, blk, 0, stream>>>(x1, wtb, out1, N, D1);
  build_csr(row1, col1, ew1);
  conv_wt<<<dim3(D1), blk, 0, stream>>>(W1, wtb, D1);
  gemm_bf16<true><<<gemm_grid, blk, 0, stream>>>(x1, wtb, hpb, N, D1);
  agg_slice<<<slice_grid, blk, 0, stream>>>(hpb, offs, sedge, out1, out1, N);
  ln_rows<<<ln_grid, blk, 0, stream>>>(out1, g1, b1, out1, N);
}